// Round 4
// baseline (204.898 us; speedup 1.0000x reference)
//
#include <hip/hip_runtime.h>
#include <cstdint>

#define BATCH 4096
#define DIN   2560
#define FDIM  2048
#define KP    2624   // packed W cols: 2560 feats + 64 bias block (all 64-mult)
#define CAP   1024   // per-bucket row capacity (n_b ~ 683 +/- 24)
#define BM    128
#define BN    128
#define BK    64

typedef unsigned short u16;
typedef __attribute__((ext_vector_type(4))) unsigned short u16x4;
typedef __attribute__((ext_vector_type(8))) unsigned short u16x8;
typedef __attribute__((ext_vector_type(8))) __bf16 bf16x8;
typedef __attribute__((ext_vector_type(4))) float f32x4;

__device__ __forceinline__ u16 f2bf(float f) {
  unsigned int u = __float_as_uint(f);
  u += 0x7FFFu + ((u >> 16) & 1u);
  return (u16)(u >> 16);
}

// bucket tables: b: 0:(0,1) 1:(0,2) 2:(0,3) 3:(1,2) 4:(1,3) 5:(2,3)
// KB[b] = d_i + d_j + 64;  FSB[b] = prefix sum of CAP*KB (u16 elements)
#define FS_TOTAL 8257536   // 1024*(1856+1344+1088+1600+1344+832)

__global__ __launch_bounds__(64) void zero_kernel(int* cnt) {
  if (threadIdx.x < 6) cnt[threadIdx.x] = 0;
}

// ---------------------------------------------------------------------------
// prep: blocks [0,2624): pack W -> bf16 WP [FDIM][KP]  (bias block at 2560)
//       blocks [2624,3648): gate -> bucket slot + compacted scaled FS row
// ---------------------------------------------------------------------------
#define PACK_BLOCKS 2624   // FDIM * (KP/8) / 256
#define GATE_BLOCKS 1024   // BATCH / 4

__global__ __launch_bounds__(256) void prep_kernel(
    const float* __restrict__ f0, const float* __restrict__ f1,
    const float* __restrict__ f2, const float* __restrict__ f3,
    const float* __restrict__ gw, const float* __restrict__ gb,
    const float* __restrict__ w0, const float* __restrict__ w1,
    const float* __restrict__ w2, const float* __restrict__ w3,
    const float* __restrict__ b0, const float* __restrict__ b1,
    const float* __restrict__ b2, const float* __restrict__ b3,
    u16* __restrict__ wp, u16* __restrict__ fs,
    int* __restrict__ cnt, int* __restrict__ table)
{
  if (blockIdx.x < PACK_BLOCKS) {
    // one thread per 16 B chunk; KP/8 = 328 chunks per row
    int chunk = blockIdx.x * 256 + threadIdx.x;
    int j = chunk / 328;
    int s = chunk - j * 328;
    u16x8 o;
    if (s < 320) {
      const float* src; int col;
      if (s < 96)       { src = w0 + j * 768;  col = s * 8; }
      else if (s < 224) { src = w1 + j * 1024; col = (s - 96) * 8; }
      else if (s < 288) { src = w2 + j * 512;  col = (s - 224) * 8; }
      else              { src = w3 + j * 256;  col = (s - 288) * 8; }
      float4 v0 = *(const float4*)(src + col);
      float4 v1 = *(const float4*)(src + col + 4);
      o[0] = f2bf(v0.x); o[1] = f2bf(v0.y); o[2] = f2bf(v0.z); o[3] = f2bf(v0.w);
      o[4] = f2bf(v1.x); o[5] = f2bf(v1.y); o[6] = f2bf(v1.z); o[7] = f2bf(v1.w);
    } else if (s == 320) {
      o[0] = f2bf(b0[j]); o[1] = f2bf(b1[j]); o[2] = f2bf(b2[j]); o[3] = f2bf(b3[j]);
      o[4] = 0; o[5] = 0; o[6] = 0; o[7] = 0;
    } else {
      o = (u16x8)(u16)0;
    }
    *(u16x8*)(wp + (size_t)j * KP + s * 8) = o;
    return;
  }

  // ---- gate: one WAVE per row
  const int wave = threadIdx.x >> 6;
  const int lane = threadIdx.x & 63;
  const int b    = (blockIdx.x - PACK_BLOCKS) * 4 + wave;

  float4 fv[10];
  float a[4] = {0.f, 0.f, 0.f, 0.f};
#pragma unroll
  for (int i = 0; i < 10; ++i) {
    int c4 = lane + i * 64;
    const float4* fp;
    if (c4 < 192)      fp = (const float4*)f0 + b * 192 + c4;
    else if (c4 < 448) fp = (const float4*)f1 + b * 256 + (c4 - 192);
    else if (c4 < 576) fp = (const float4*)f2 + b * 128 + (c4 - 448);
    else               fp = (const float4*)f3 + b * 64  + (c4 - 576);
    float4 v = *fp;
    fv[i] = v;
#pragma unroll
    for (int e = 0; e < 4; ++e) {
      float4 g = *((const float4*)(gw + e * DIN) + c4);
      a[e] += v.x * g.x + v.y * g.y + v.z * g.z + v.w * g.w;
    }
  }
#pragma unroll
  for (int e = 0; e < 4; ++e) {
#pragma unroll
    for (int m = 32; m >= 1; m >>= 1) a[e] += __shfl_xor(a[e], m, 64);
    a[e] += gb[e];
  }

  float mx = fmaxf(fmaxf(a[0], a[1]), fmaxf(a[2], a[3]));
  float ex[4], ssum = 0.f;
#pragma unroll
  for (int e = 0; e < 4; ++e) { ex[e] = __expf(a[e] - mx); ssum += ex[e]; }
  int i1 = 0;
#pragma unroll
  for (int e = 1; e < 4; ++e) if (a[e] > a[i1]) i1 = e;
  int i2 = -1;
#pragma unroll
  for (int e = 0; e < 4; ++e) {
    if (e == i1) continue;
    if (i2 < 0 || a[e] > a[i2]) i2 = e;
  }
  float inv = 1.f / ssum;
  float g[4];
#pragma unroll
  for (int e = 0; e < 4; ++e) g[e] = (e == i1 || e == i2) ? ex[e] * inv : 0.f;

  const int lo = min(i1, i2), hi = max(i1, i2);
  const int bucket = (lo == 0) ? (hi - 1) : (lo == 1) ? (hi + 1) : 5;

  int slot = 0;
  if (lane == 0) {
    slot = atomicAdd(&cnt[bucket], 1);
    table[bucket * CAP + slot] = b;
  }
  slot = __shfl(slot, 0, 64);

  const int KB6[6]  = {1856, 1344, 1088, 1600, 1344, 832};
  const int FSB6[6] = {0, 1900544, 3276800, 4390912, 6029312, 7405568};
  const int DL[4]   = {768, 1024, 512, 256};
  const int S0[4]   = {0, 192, 448, 576};       // src starts (float4 units)
  const int EX[10]  = {0, 0, 0, 1, 1, 1, 1, 2, 2, 3};

  const int dlo4 = DL[lo] >> 2;
  u16* row = fs + FSB6[bucket] + (size_t)slot * KB6[bucket];
#pragma unroll
  for (int i = 0; i < 10; ++i) {
    const int e  = EX[i];
    const int c4 = lane + i * 64;
    if (e == lo || e == hi) {
      int dst = (c4 - S0[e]) + ((e == hi) ? dlo4 : 0);
      float gg = g[e];
      u16x4 o = { f2bf(fv[i].x * gg), f2bf(fv[i].y * gg),
                  f2bf(fv[i].z * gg), f2bf(fv[i].w * gg) };
      *(u16x4*)(row + dst * 4) = o;
    }
  }
  // bias block: 64 cols at d_lo+d_hi; col e = g_e (zeros elsewhere, must clear)
  if (lane < 16) {
    int base = DL[lo] + DL[hi];
    u16x4 o = { (u16)0, (u16)0, (u16)0, (u16)0 };
    if (lane == 0) { o[0] = f2bf(g[0]); o[1] = f2bf(g[1]);
                     o[2] = f2bf(g[2]); o[3] = f2bf(g[3]); }
    *(u16x4*)(row + base + lane * 4) = o;
  }
}

// ---------------------------------------------------------------------------
// gemm: per-bucket C[rows(b)][2048] = FS_b @ [w_i|w_j|bias]^T
// 128x128 tile, BK=64, 8 waves (wave tile 64x32), 8-way XOR swizzle,
// global_load_lds width 16. Fixed grid 6*8*16; early-exit by count.
// ---------------------------------------------------------------------------
__device__ __forceinline__ void gld16(const u16* g, u16* l) {
  __builtin_amdgcn_global_load_lds(
      (const __attribute__((address_space(1))) unsigned int*)(uintptr_t)g,
      (__attribute__((address_space(3))) unsigned int*)(unsigned int)(uintptr_t)l,
      16, 0, 0);
}

__global__ __launch_bounds__(512, 4) void gemm_kernel(
    const u16* __restrict__ fs, const u16* __restrict__ wp,
    const int* __restrict__ cnt, const int* __restrict__ table,
    float* __restrict__ C)
{
  const int KB6[6]  = {1856, 1344, 1088, 1600, 1344, 832};
  const int FSB6[6] = {0, 1900544, 3276800, 4390912, 6029312, 7405568};
  const int LOE[6]  = {0, 0, 0, 1, 1, 2};
  const int HIE[6]  = {1, 2, 3, 2, 3, 3};
  const int WOFF[4] = {0, 768, 1792, 2304};
  const int DL[4]   = {768, 1024, 512, 256};

  const int bucket = blockIdx.x >> 7;
  const int rr     = blockIdx.x & 127;
  const int mtile  = rr >> 4;
  const int ntile  = rr & 15;
  const int nb     = cnt[bucket];
  if (mtile * BM >= nb) return;

  const int kb = KB6[bucket];
  const int di = DL[LOE[bucket]], dj = DL[HIE[bucket]];
  const int wi = WOFF[LOE[bucket]], wj = WOFF[HIE[bucket]];

  __shared__ u16 As[BM * BK];    // 16 KB
  __shared__ u16 Bs[BN * BK];    // 16 KB

  const int tid  = threadIdx.x;
  const int wave = tid >> 6;
  const int lane = tid & 63;
  const int wm   = (wave >> 2) * 64;  // 2x4 wave grid, wave tile 64x32
  const int wn   = (wave & 3) * 32;
  const int qd   = lane >> 4;
  const int l15  = lane & 15;

  // staging: 1024 chunks (16 B) per tile; thread handles idx and idx+512.
  // LDS[row][slot] <- G[row][slot ^ (row&7)]  (8-way XOR swizzle)
  const int r0 = tid >> 3,           s0c = ((tid & 7) ^ (r0 & 7)) * 8;
  const int r1 = (tid + 512) >> 3,   s1c = ((tid & 7) ^ (r1 & 7)) * 8;

  const u16* Ab = fs + FSB6[bucket] + (size_t)(mtile * BM) * kb;
  const u16* Bb = wp + (size_t)(ntile * BN) * KP;

  f32x4 acc[4][2] = {};

  for (int k0 = 0; k0 < kb; k0 += BK) {
    const int bcol = (k0 < di) ? wi + k0
                   : (k0 < di + dj) ? wj + (k0 - di)
                   : 2560 + (k0 - di - dj);
    gld16(Ab + (size_t)r0 * kb + k0 + s0c, &As[tid * 8]);
    gld16(Ab + (size_t)r1 * kb + k0 + s1c, &As[(tid + 512) * 8]);
    gld16(Bb + (size_t)r0 * KP + bcol + s0c, &Bs[tid * 8]);
    gld16(Bb + (size_t)r1 * KP + bcol + s1c, &Bs[(tid + 512) * 8]);
    __syncthreads();

#pragma unroll
    for (int h = 0; h < 2; ++h) {
      const int sw = ((qd + 4 * h) ^ (l15 & 7)) * 8;   // de-swizzle
      bf16x8 af[4], bfr[2];
#pragma unroll
      for (int r = 0; r < 4; ++r)
        af[r] = __builtin_bit_cast(bf16x8,
                  *(const u16x8*)&As[(wm + r * 16 + l15) * BK + sw]);
#pragma unroll
      for (int c = 0; c < 2; ++c)
        bfr[c] = __builtin_bit_cast(bf16x8,
                  *(const u16x8*)&Bs[(wn + c * 16 + l15) * BK + sw]);
#pragma unroll
      for (int r = 0; r < 4; ++r)
#pragma unroll
        for (int c = 0; c < 2; ++c)
          acc[r][c] = __builtin_amdgcn_mfma_f32_16x16x32_bf16(af[r], bfr[c],
                                                              acc[r][c], 0, 0, 0);
    }
    __syncthreads();
  }

  // epilogue: scatter rows via table; C/D layout col=lane&15, row=quad*4+reg
#pragma unroll
  for (int r = 0; r < 4; ++r) {
#pragma unroll
    for (int i = 0; i < 4; ++i) {
      const int slot = mtile * BM + wm + r * 16 + qd * 4 + i;
      if (slot < nb) {
        const int rowg = table[bucket * CAP + slot];
#pragma unroll
        for (int c = 0; c < 2; ++c) {
          const int col = ntile * BN + wn + c * 16 + l15;
          C[(size_t)rowg * FDIM + col] = acc[r][c][i];
        }
      }
    }
  }
}

// ---------------------------------------------------------------------------
extern "C" void kernel_launch(void* const* d_in, const int* in_sizes, int n_in,
                              void* d_out, int out_size, void* d_ws, size_t ws_size,
                              hipStream_t stream) {
  (void)in_sizes; (void)n_in; (void)out_size; (void)ws_size;
  const float* f0 = (const float*)d_in[0];
  const float* f1 = (const float*)d_in[1];
  const float* f2 = (const float*)d_in[2];
  const float* f3 = (const float*)d_in[3];
  const float* gw = (const float*)d_in[4];
  const float* gb = (const float*)d_in[5];
  const float* w0 = (const float*)d_in[6];
  const float* b0 = (const float*)d_in[7];
  const float* w1 = (const float*)d_in[8];
  const float* b1 = (const float*)d_in[9];
  const float* w2 = (const float*)d_in[10];
  const float* b2 = (const float*)d_in[11];
  const float* w3 = (const float*)d_in[12];
  const float* b3 = (const float*)d_in[13];
  float* out = (float*)d_out;

  char* ws = (char*)d_ws;
  u16* wp    = (u16*)ws;                                   // 2048*2624*2 B
  u16* fs    = (u16*)(ws + (size_t)FDIM * KP * 2);         // FS_TOTAL*2 B
  int* cnt   = (int*)(ws + (size_t)FDIM * KP * 2 + (size_t)FS_TOTAL * 2);
  int* table = cnt + 16;                                   // 6*CAP ints

  hipLaunchKernelGGL(zero_kernel, dim3(1), dim3(64), 0, stream, cnt);
  hipLaunchKernelGGL(prep_kernel, dim3(PACK_BLOCKS + GATE_BLOCKS), dim3(256), 0,
                     stream, f0, f1, f2, f3, gw, gb,
                     w0, w1, w2, w3, b0, b1, b2, b3, wp, fs, cnt, table);
  hipLaunchKernelGGL(gemm_kernel, dim3(6 * 8 * 16), dim3(512), 0, stream,
                     fs, wp, cnt, table, out);
}

// Round 5
// 171.871 us; speedup vs baseline: 1.1922x; 1.1922x over previous
//
#include <hip/hip_runtime.h>
#include <cstdint>

#define BATCH 4096
#define DIN   2560
#define FDIM  2048
#define KP    2624   // packed W cols: 2560 feats + 64 bias block (all 64-mult)
#define CAP   1024   // per-bucket row capacity (n_b ~ 683 +/- 24)
#define BM    128
#define BN    128
#define BK    64

typedef unsigned short u16;
typedef __attribute__((ext_vector_type(4))) unsigned short u16x4;
typedef __attribute__((ext_vector_type(8))) unsigned short u16x8;
typedef __attribute__((ext_vector_type(8))) __bf16 bf16x8;
typedef __attribute__((ext_vector_type(4))) float f32x4;

__device__ __forceinline__ u16 f2bf(float f) {
  unsigned int u = __float_as_uint(f);
  u += 0x7FFFu + ((u >> 16) & 1u);
  return (u16)(u >> 16);
}

// bucket tables: b: 0:(0,1) 1:(0,2) 2:(0,3) 3:(1,2) 4:(1,3) 5:(2,3)
// KB[b] = d_i + d_j + 64;  FSB[b] = prefix sum of CAP*KB (u16 elements)
#define FS_TOTAL 8257536   // 1024*(1856+1344+1088+1600+1344+832)

__global__ __launch_bounds__(64) void zero_kernel(int* cnt) {
  if (threadIdx.x < 6) cnt[threadIdx.x] = 0;
}

// ---------------------------------------------------------------------------
// prep (512 thr): blocks [0,256): grid-stride pack W -> bf16 WP [FDIM][KP]
//                 blocks [256,768): gate (8 rows/block) -> compacted FS rows
// ---------------------------------------------------------------------------
#define PACK_BLOCKS 256
#define GATE_BLOCKS 512    // BATCH / 8

__global__ __launch_bounds__(512) void prep_kernel(
    const float* __restrict__ f0, const float* __restrict__ f1,
    const float* __restrict__ f2, const float* __restrict__ f3,
    const float* __restrict__ gw, const float* __restrict__ gb,
    const float* __restrict__ w0, const float* __restrict__ w1,
    const float* __restrict__ w2, const float* __restrict__ w3,
    const float* __restrict__ b0, const float* __restrict__ b1,
    const float* __restrict__ b2, const float* __restrict__ b3,
    u16* __restrict__ wp, u16* __restrict__ fs,
    int* __restrict__ cnt, int* __restrict__ table)
{
  if (blockIdx.x < PACK_BLOCKS) {
    // grid-stride over 16 B chunks; KP/8 = 328 chunks per row
    const int total = FDIM * (KP / 8);   // 671744
    for (int chunk = blockIdx.x * 512 + threadIdx.x; chunk < total;
         chunk += PACK_BLOCKS * 512) {
      int j = chunk / 328;
      int s = chunk - j * 328;
      u16x8 o;
      if (s < 320) {
        const float* src; int col;
        if (s < 96)       { src = w0 + j * 768;  col = s * 8; }
        else if (s < 224) { src = w1 + j * 1024; col = (s - 96) * 8; }
        else if (s < 288) { src = w2 + j * 512;  col = (s - 224) * 8; }
        else              { src = w3 + j * 256;  col = (s - 288) * 8; }
        float4 v0 = *(const float4*)(src + col);
        float4 v1 = *(const float4*)(src + col + 4);
        o[0] = f2bf(v0.x); o[1] = f2bf(v0.y); o[2] = f2bf(v0.z); o[3] = f2bf(v0.w);
        o[4] = f2bf(v1.x); o[5] = f2bf(v1.y); o[6] = f2bf(v1.z); o[7] = f2bf(v1.w);
      } else if (s == 320) {
        o[0] = f2bf(b0[j]); o[1] = f2bf(b1[j]); o[2] = f2bf(b2[j]); o[3] = f2bf(b3[j]);
        o[4] = 0; o[5] = 0; o[6] = 0; o[7] = 0;
      } else {
        o = (u16x8)(u16)0;
      }
      *(u16x8*)(wp + (size_t)j * KP + s * 8) = o;
    }
    return;
  }

  // ---- gate: one WAVE per row, 8 rows per block
  const int wave = threadIdx.x >> 6;
  const int lane = threadIdx.x & 63;
  const int b    = (blockIdx.x - PACK_BLOCKS) * 8 + wave;

  float4 fv[10];
  float a[4] = {0.f, 0.f, 0.f, 0.f};
#pragma unroll
  for (int i = 0; i < 10; ++i) {
    int c4 = lane + i * 64;
    const float4* fp;
    if (c4 < 192)      fp = (const float4*)f0 + b * 192 + c4;
    else if (c4 < 448) fp = (const float4*)f1 + b * 256 + (c4 - 192);
    else if (c4 < 576) fp = (const float4*)f2 + b * 128 + (c4 - 448);
    else               fp = (const float4*)f3 + b * 64  + (c4 - 576);
    float4 v = *fp;
    fv[i] = v;
#pragma unroll
    for (int e = 0; e < 4; ++e) {
      float4 g = *((const float4*)(gw + e * DIN) + c4);
      a[e] += v.x * g.x + v.y * g.y + v.z * g.z + v.w * g.w;
    }
  }
#pragma unroll
  for (int e = 0; e < 4; ++e) {
#pragma unroll
    for (int m = 32; m >= 1; m >>= 1) a[e] += __shfl_xor(a[e], m, 64);
    a[e] += gb[e];
  }

  float mx = fmaxf(fmaxf(a[0], a[1]), fmaxf(a[2], a[3]));
  float ex[4], ssum = 0.f;
#pragma unroll
  for (int e = 0; e < 4; ++e) { ex[e] = __expf(a[e] - mx); ssum += ex[e]; }
  int i1 = 0;
#pragma unroll
  for (int e = 1; e < 4; ++e) if (a[e] > a[i1]) i1 = e;
  int i2 = -1;
#pragma unroll
  for (int e = 0; e < 4; ++e) {
    if (e == i1) continue;
    if (i2 < 0 || a[e] > a[i2]) i2 = e;
  }
  float inv = 1.f / ssum;
  float g[4];
#pragma unroll
  for (int e = 0; e < 4; ++e) g[e] = (e == i1 || e == i2) ? ex[e] * inv : 0.f;

  const int lo = min(i1, i2), hi = max(i1, i2);
  const int bucket = (lo == 0) ? (hi - 1) : (lo == 1) ? (hi + 1) : 5;

  // block-aggregated slot assignment: <=6 atomics per block, amortized 8 rows
  __shared__ int bkt[8];
  __shared__ int base6[6];
  if (lane == 0) bkt[wave] = bucket;
  __syncthreads();
  if (threadIdx.x < 6) {
    int c = 0;
#pragma unroll
    for (int w = 0; w < 8; ++w) c += (bkt[w] == (int)threadIdx.x);
    base6[threadIdx.x] = c ? atomicAdd(&cnt[threadIdx.x], c) : 0;
  }
  __syncthreads();
  int rank = 0;
  for (int w = 0; w < wave; ++w) rank += (bkt[w] == bucket);
  const int slot = base6[bucket] + rank;
  if (lane == 0) table[bucket * CAP + slot] = b;

  const int KB6[6]  = {1856, 1344, 1088, 1600, 1344, 832};
  const int FSB6[6] = {0, 1900544, 3276800, 4390912, 6029312, 7405568};
  const int DL[4]   = {768, 1024, 512, 256};
  const int S0[4]   = {0, 192, 448, 576};       // src starts (float4 units)
  const int EX[10]  = {0, 0, 0, 1, 1, 1, 1, 2, 2, 3};

  const int dlo4 = DL[lo] >> 2;
  u16* row = fs + FSB6[bucket] + (size_t)slot * KB6[bucket];
#pragma unroll
  for (int i = 0; i < 10; ++i) {
    const int e  = EX[i];
    const int c4 = lane + i * 64;
    if (e == lo || e == hi) {
      int dst = (c4 - S0[e]) + ((e == hi) ? dlo4 : 0);
      float gg = g[e];
      u16x4 o = { f2bf(fv[i].x * gg), f2bf(fv[i].y * gg),
                  f2bf(fv[i].z * gg), f2bf(fv[i].w * gg) };
      *(u16x4*)(row + dst * 4) = o;
    }
  }
  // bias block: 64 cols at d_lo+d_hi; col e = g_e (zeros elsewhere, must clear)
  if (lane < 16) {
    int base = DL[lo] + DL[hi];
    u16x4 o = { (u16)0, (u16)0, (u16)0, (u16)0 };
    if (lane == 0) { o[0] = f2bf(g[0]); o[1] = f2bf(g[1]);
                     o[2] = f2bf(g[2]); o[3] = f2bf(g[3]); }
    *(u16x4*)(row + base + lane * 4) = o;
  }
}

// ---------------------------------------------------------------------------
// gemm: per-bucket C[rows(b)][2048] = FS_b @ [w_i|w_j|bias]^T
// 128x128 tile, BK=64, 8 waves (wave tile 64x32), 8-way XOR swizzle,
// global_load_lds width 16. Fixed grid 6*8*16; early-exit by count.
// (byte-identical to R4 gemm)
// ---------------------------------------------------------------------------
__device__ __forceinline__ void gld16(const u16* g, u16* l) {
  __builtin_amdgcn_global_load_lds(
      (const __attribute__((address_space(1))) unsigned int*)(uintptr_t)g,
      (__attribute__((address_space(3))) unsigned int*)(unsigned int)(uintptr_t)l,
      16, 0, 0);
}

__global__ __launch_bounds__(512, 4) void gemm_kernel(
    const u16* __restrict__ fs, const u16* __restrict__ wp,
    const int* __restrict__ cnt, const int* __restrict__ table,
    float* __restrict__ C)
{
  const int KB6[6]  = {1856, 1344, 1088, 1600, 1344, 832};
  const int FSB6[6] = {0, 1900544, 3276800, 4390912, 6029312, 7405568};
  const int LOE[6]  = {0, 0, 0, 1, 1, 2};
  const int HIE[6]  = {1, 2, 3, 2, 3, 3};
  const int WOFF[4] = {0, 768, 1792, 2304};
  const int DL[4]   = {768, 1024, 512, 256};

  const int bucket = blockIdx.x >> 7;
  const int rr     = blockIdx.x & 127;
  const int mtile  = rr >> 4;
  const int ntile  = rr & 15;
  const int nb     = cnt[bucket];
  if (mtile * BM >= nb) return;

  const int kb = KB6[bucket];
  const int di = DL[LOE[bucket]], dj = DL[HIE[bucket]];
  const int wi = WOFF[LOE[bucket]], wj = WOFF[HIE[bucket]];

  __shared__ u16 As[BM * BK];    // 16 KB
  __shared__ u16 Bs[BN * BK];    // 16 KB

  const int tid  = threadIdx.x;
  const int wave = tid >> 6;
  const int lane = tid & 63;
  const int wm   = (wave >> 2) * 64;  // 2x4 wave grid, wave tile 64x32
  const int wn   = (wave & 3) * 32;
  const int qd   = lane >> 4;
  const int l15  = lane & 15;

  // staging: 1024 chunks (16 B) per tile; thread handles idx and idx+512.
  // LDS[row][slot] <- G[row][slot ^ (row&7)]  (8-way XOR swizzle)
  const int r0 = tid >> 3,           s0c = ((tid & 7) ^ (r0 & 7)) * 8;
  const int r1 = (tid + 512) >> 3,   s1c = ((tid & 7) ^ (r1 & 7)) * 8;

  const u16* Ab = fs + FSB6[bucket] + (size_t)(mtile * BM) * kb;
  const u16* Bb = wp + (size_t)(ntile * BN) * KP;

  f32x4 acc[4][2] = {};

  for (int k0 = 0; k0 < kb; k0 += BK) {
    const int bcol = (k0 < di) ? wi + k0
                   : (k0 < di + dj) ? wj + (k0 - di)
                   : 2560 + (k0 - di - dj);
    gld16(Ab + (size_t)r0 * kb + k0 + s0c, &As[tid * 8]);
    gld16(Ab + (size_t)r1 * kb + k0 + s1c, &As[(tid + 512) * 8]);
    gld16(Bb + (size_t)r0 * KP + bcol + s0c, &Bs[tid * 8]);
    gld16(Bb + (size_t)r1 * KP + bcol + s1c, &Bs[(tid + 512) * 8]);
    __syncthreads();

#pragma unroll
    for (int h = 0; h < 2; ++h) {
      const int sw = ((qd + 4 * h) ^ (l15 & 7)) * 8;   // de-swizzle
      bf16x8 af[4], bfr[2];
#pragma unroll
      for (int r = 0; r < 4; ++r)
        af[r] = __builtin_bit_cast(bf16x8,
                  *(const u16x8*)&As[(wm + r * 16 + l15) * BK + sw]);
#pragma unroll
      for (int c = 0; c < 2; ++c)
        bfr[c] = __builtin_bit_cast(bf16x8,
                  *(const u16x8*)&Bs[(wn + c * 16 + l15) * BK + sw]);
#pragma unroll
      for (int r = 0; r < 4; ++r)
#pragma unroll
        for (int c = 0; c < 2; ++c)
          acc[r][c] = __builtin_amdgcn_mfma_f32_16x16x32_bf16(af[r], bfr[c],
                                                              acc[r][c], 0, 0, 0);
    }
    __syncthreads();
  }

  // epilogue: scatter rows via table; C/D layout col=lane&15, row=quad*4+reg
#pragma unroll
  for (int r = 0; r < 4; ++r) {
#pragma unroll
    for (int i = 0; i < 4; ++i) {
      const int slot = mtile * BM + wm + r * 16 + qd * 4 + i;
      if (slot < nb) {
        const int rowg = table[bucket * CAP + slot];
#pragma unroll
        for (int c = 0; c < 2; ++c) {
          const int col = ntile * BN + wn + c * 16 + l15;
          C[(size_t)rowg * FDIM + col] = acc[r][c][i];
        }
      }
    }
  }
}

// ---------------------------------------------------------------------------
extern "C" void kernel_launch(void* const* d_in, const int* in_sizes, int n_in,
                              void* d_out, int out_size, void* d_ws, size_t ws_size,
                              hipStream_t stream) {
  (void)in_sizes; (void)n_in; (void)out_size; (void)ws_size;
  const float* f0 = (const float*)d_in[0];
  const float* f1 = (const float*)d_in[1];
  const float* f2 = (const float*)d_in[2];
  const float* f3 = (const float*)d_in[3];
  const float* gw = (const float*)d_in[4];
  const float* gb = (const float*)d_in[5];
  const float* w0 = (const float*)d_in[6];
  const float* b0 = (const float*)d_in[7];
  const float* w1 = (const float*)d_in[8];
  const float* b1 = (const float*)d_in[9];
  const float* w2 = (const float*)d_in[10];
  const float* b2 = (const float*)d_in[11];
  const float* w3 = (const float*)d_in[12];
  const float* b3 = (const float*)d_in[13];
  float* out = (float*)d_out;

  char* ws = (char*)d_ws;
  u16* wp    = (u16*)ws;                                   // 2048*2624*2 B
  u16* fs    = (u16*)(ws + (size_t)FDIM * KP * 2);         // FS_TOTAL*2 B
  int* cnt   = (int*)(ws + (size_t)FDIM * KP * 2 + (size_t)FS_TOTAL * 2);
  int* table = cnt + 16;                                   // 6*CAP ints

  hipLaunchKernelGGL(zero_kernel, dim3(1), dim3(64), 0, stream, cnt);
  hipLaunchKernelGGL(prep_kernel, dim3(PACK_BLOCKS + GATE_BLOCKS), dim3(512), 0,
                     stream, f0, f1, f2, f3, gw, gb,
                     w0, w1, w2, w3, b0, b1, b2, b3, wp, fs, cnt, table);
  hipLaunchKernelGGL(gemm_kernel, dim3(6 * 8 * 16), dim3(512), 0, stream,
                     fs, wp, cnt, table, out);
}

// Round 6
// 169.965 us; speedup vs baseline: 1.2055x; 1.0112x over previous
//
#include <hip/hip_runtime.h>
#include <cstdint>

#define BATCH 4096
#define DIN   2560
#define FDIM  2048
#define KP    2624   // packed W cols: 2560 feats + 64 bias block (all 64-mult)
#define CAP   1024   // per-bucket row capacity (n_b ~ 683 +/- 24)
#define BM    64
#define BN    128
#define BK    64

typedef unsigned short u16;
typedef __attribute__((ext_vector_type(4))) unsigned short u16x4;
typedef __attribute__((ext_vector_type(8))) unsigned short u16x8;
typedef __attribute__((ext_vector_type(8))) __bf16 bf16x8;
typedef __attribute__((ext_vector_type(4))) float f32x4;

__device__ __forceinline__ u16 f2bf(float f) {
  unsigned int u = __float_as_uint(f);
  u += 0x7FFFu + ((u >> 16) & 1u);
  return (u16)(u >> 16);
}

// bucket tables: b: 0:(0,1) 1:(0,2) 2:(0,3) 3:(1,2) 4:(1,3) 5:(2,3)
// KB[b] = d_i + d_j + 64;  FSB[b] = prefix sum of CAP*KB (u16 elements)
#define FS_TOTAL 8257536   // 1024*(1856+1344+1088+1600+1344+832)

__global__ __launch_bounds__(64) void zero_kernel(int* cnt) {
  if (threadIdx.x < 6) cnt[threadIdx.x] = 0;
}

// ---------------------------------------------------------------------------
// prep (512 thr): blocks [0,256): grid-stride pack W -> bf16 WP [FDIM][KP]
//                 blocks [256,768): gate (8 rows/block) -> compacted FS rows
// (byte-identical to R5 prep)
// ---------------------------------------------------------------------------
#define PACK_BLOCKS 256
#define GATE_BLOCKS 512    // BATCH / 8

__global__ __launch_bounds__(512) void prep_kernel(
    const float* __restrict__ f0, const float* __restrict__ f1,
    const float* __restrict__ f2, const float* __restrict__ f3,
    const float* __restrict__ gw, const float* __restrict__ gb,
    const float* __restrict__ w0, const float* __restrict__ w1,
    const float* __restrict__ w2, const float* __restrict__ w3,
    const float* __restrict__ b0, const float* __restrict__ b1,
    const float* __restrict__ b2, const float* __restrict__ b3,
    u16* __restrict__ wp, u16* __restrict__ fs,
    int* __restrict__ cnt, int* __restrict__ table)
{
  if (blockIdx.x < PACK_BLOCKS) {
    // grid-stride over 16 B chunks; KP/8 = 328 chunks per row
    const int total = FDIM * (KP / 8);   // 671744
    for (int chunk = blockIdx.x * 512 + threadIdx.x; chunk < total;
         chunk += PACK_BLOCKS * 512) {
      int j = chunk / 328;
      int s = chunk - j * 328;
      u16x8 o;
      if (s < 320) {
        const float* src; int col;
        if (s < 96)       { src = w0 + j * 768;  col = s * 8; }
        else if (s < 224) { src = w1 + j * 1024; col = (s - 96) * 8; }
        else if (s < 288) { src = w2 + j * 512;  col = (s - 224) * 8; }
        else              { src = w3 + j * 256;  col = (s - 288) * 8; }
        float4 v0 = *(const float4*)(src + col);
        float4 v1 = *(const float4*)(src + col + 4);
        o[0] = f2bf(v0.x); o[1] = f2bf(v0.y); o[2] = f2bf(v0.z); o[3] = f2bf(v0.w);
        o[4] = f2bf(v1.x); o[5] = f2bf(v1.y); o[6] = f2bf(v1.z); o[7] = f2bf(v1.w);
      } else if (s == 320) {
        o[0] = f2bf(b0[j]); o[1] = f2bf(b1[j]); o[2] = f2bf(b2[j]); o[3] = f2bf(b3[j]);
        o[4] = 0; o[5] = 0; o[6] = 0; o[7] = 0;
      } else {
        o = (u16x8)(u16)0;
      }
      *(u16x8*)(wp + (size_t)j * KP + s * 8) = o;
    }
    return;
  }

  // ---- gate: one WAVE per row, 8 rows per block
  const int wave = threadIdx.x >> 6;
  const int lane = threadIdx.x & 63;
  const int b    = (blockIdx.x - PACK_BLOCKS) * 8 + wave;

  float4 fv[10];
  float a[4] = {0.f, 0.f, 0.f, 0.f};
#pragma unroll
  for (int i = 0; i < 10; ++i) {
    int c4 = lane + i * 64;
    const float4* fp;
    if (c4 < 192)      fp = (const float4*)f0 + b * 192 + c4;
    else if (c4 < 448) fp = (const float4*)f1 + b * 256 + (c4 - 192);
    else if (c4 < 576) fp = (const float4*)f2 + b * 128 + (c4 - 448);
    else               fp = (const float4*)f3 + b * 64  + (c4 - 576);
    float4 v = *fp;
    fv[i] = v;
#pragma unroll
    for (int e = 0; e < 4; ++e) {
      float4 g = *((const float4*)(gw + e * DIN) + c4);
      a[e] += v.x * g.x + v.y * g.y + v.z * g.z + v.w * g.w;
    }
  }
#pragma unroll
  for (int e = 0; e < 4; ++e) {
#pragma unroll
    for (int m = 32; m >= 1; m >>= 1) a[e] += __shfl_xor(a[e], m, 64);
    a[e] += gb[e];
  }

  float mx = fmaxf(fmaxf(a[0], a[1]), fmaxf(a[2], a[3]));
  float ex[4], ssum = 0.f;
#pragma unroll
  for (int e = 0; e < 4; ++e) { ex[e] = __expf(a[e] - mx); ssum += ex[e]; }
  int i1 = 0;
#pragma unroll
  for (int e = 1; e < 4; ++e) if (a[e] > a[i1]) i1 = e;
  int i2 = -1;
#pragma unroll
  for (int e = 0; e < 4; ++e) {
    if (e == i1) continue;
    if (i2 < 0 || a[e] > a[i2]) i2 = e;
  }
  float inv = 1.f / ssum;
  float g[4];
#pragma unroll
  for (int e = 0; e < 4; ++e) g[e] = (e == i1 || e == i2) ? ex[e] * inv : 0.f;

  const int lo = min(i1, i2), hi = max(i1, i2);
  const int bucket = (lo == 0) ? (hi - 1) : (lo == 1) ? (hi + 1) : 5;

  // block-aggregated slot assignment: <=6 atomics per block, amortized 8 rows
  __shared__ int bkt[8];
  __shared__ int base6[6];
  if (lane == 0) bkt[wave] = bucket;
  __syncthreads();
  if (threadIdx.x < 6) {
    int c = 0;
#pragma unroll
    for (int w = 0; w < 8; ++w) c += (bkt[w] == (int)threadIdx.x);
    base6[threadIdx.x] = c ? atomicAdd(&cnt[threadIdx.x], c) : 0;
  }
  __syncthreads();
  int rank = 0;
  for (int w = 0; w < wave; ++w) rank += (bkt[w] == bucket);
  const int slot = base6[bucket] + rank;
  if (lane == 0) table[bucket * CAP + slot] = b;

  const int KB6[6]  = {1856, 1344, 1088, 1600, 1344, 832};
  const int FSB6[6] = {0, 1900544, 3276800, 4390912, 6029312, 7405568};
  const int DL[4]   = {768, 1024, 512, 256};
  const int S0[4]   = {0, 192, 448, 576};       // src starts (float4 units)
  const int EX[10]  = {0, 0, 0, 1, 1, 1, 1, 2, 2, 3};

  const int dlo4 = DL[lo] >> 2;
  u16* row = fs + FSB6[bucket] + (size_t)slot * KB6[bucket];
#pragma unroll
  for (int i = 0; i < 10; ++i) {
    const int e  = EX[i];
    const int c4 = lane + i * 64;
    if (e == lo || e == hi) {
      int dst = (c4 - S0[e]) + ((e == hi) ? dlo4 : 0);
      float gg = g[e];
      u16x4 o = { f2bf(fv[i].x * gg), f2bf(fv[i].y * gg),
                  f2bf(fv[i].z * gg), f2bf(fv[i].w * gg) };
      *(u16x4*)(row + dst * 4) = o;
    }
  }
  // bias block: 64 cols at d_lo+d_hi; col e = g_e (zeros elsewhere, must clear)
  if (lane < 16) {
    int base = DL[lo] + DL[hi];
    u16x4 o = { (u16)0, (u16)0, (u16)0, (u16)0 };
    if (lane == 0) { o[0] = f2bf(g[0]); o[1] = f2bf(g[1]);
                     o[2] = f2bf(g[2]); o[3] = f2bf(g[3]); }
    *(u16x4*)(row + base + lane * 4) = o;
  }
}

// ---------------------------------------------------------------------------
// gemm: per-bucket C[rows(b)][2048] = FS_b @ [w_i|w_j|bias]^T
// 64x128 tile, BK=64, 8 waves (wave tile 32x32, acc 2x2), 8-way XOR swizzle,
// global_load_lds width 16. Grid 6*16*16 = 1536 (~4.1 active blocks/CU);
// early-exit by count. LDS 24 KB -> 4 resident blocks = 32 waves/CU.
// ---------------------------------------------------------------------------
__device__ __forceinline__ void gld16(const u16* g, u16* l) {
  __builtin_amdgcn_global_load_lds(
      (const __attribute__((address_space(1))) unsigned int*)(uintptr_t)g,
      (__attribute__((address_space(3))) unsigned int*)(unsigned int)(uintptr_t)l,
      16, 0, 0);
}

__global__ __launch_bounds__(512, 8) void gemm_kernel(
    const u16* __restrict__ fs, const u16* __restrict__ wp,
    const int* __restrict__ cnt, const int* __restrict__ table,
    float* __restrict__ C)
{
  const int KB6[6]  = {1856, 1344, 1088, 1600, 1344, 832};
  const int FSB6[6] = {0, 1900544, 3276800, 4390912, 6029312, 7405568};
  const int LOE[6]  = {0, 0, 0, 1, 1, 2};
  const int HIE[6]  = {1, 2, 3, 2, 3, 3};
  const int WOFF[4] = {0, 768, 1792, 2304};
  const int DL[4]   = {768, 1024, 512, 256};

  const int bucket = blockIdx.x >> 8;       // 256 tiles per bucket
  const int rr     = blockIdx.x & 255;
  const int mtile  = rr >> 4;               // 16 mtiles of 64 rows (CAP=1024)
  const int ntile  = rr & 15;
  const int nb     = cnt[bucket];
  if (mtile * BM >= nb) return;

  const int kb = KB6[bucket];
  const int di = DL[LOE[bucket]], dj = DL[HIE[bucket]];
  const int wi = WOFF[LOE[bucket]], wj = WOFF[HIE[bucket]];

  __shared__ u16 As[BM * BK];    // 8 KB
  __shared__ u16 Bs[BN * BK];    // 16 KB

  const int tid  = threadIdx.x;
  const int wave = tid >> 6;
  const int lane = tid & 63;
  const int wm   = (wave >> 2) * 32;  // 2x4 wave grid, wave tile 32x32
  const int wn   = (wave & 3) * 32;
  const int qd   = lane >> 4;
  const int l15  = lane & 15;

  // staging: A = 512 chunks (16 B), B = 1024 chunks; 1 A + 2 B per thread.
  // LDS[row][slot] <- G[row][slot ^ (row&7)]  (8-way XOR swizzle)
  const int arow = tid >> 3,          acol = ((tid & 7) ^ (arow & 7)) * 8;
  const int br0  = tid >> 3,          bc0  = ((tid & 7) ^ (br0 & 7)) * 8;
  const int br1  = (tid + 512) >> 3,  bc1  = ((tid & 7) ^ (br1 & 7)) * 8;

  const u16* Ab = fs + FSB6[bucket] + (size_t)(mtile * BM) * kb;
  const u16* Bb = wp + (size_t)(ntile * BN) * KP;

  f32x4 acc[2][2] = {};

  for (int k0 = 0; k0 < kb; k0 += BK) {
    const int bcol = (k0 < di) ? wi + k0
                   : (k0 < di + dj) ? wj + (k0 - di)
                   : 2560 + (k0 - di - dj);
    gld16(Ab + (size_t)arow * kb + k0 + acol, &As[tid * 8]);
    gld16(Bb + (size_t)br0 * KP + bcol + bc0, &Bs[tid * 8]);
    gld16(Bb + (size_t)br1 * KP + bcol + bc1, &Bs[(tid + 512) * 8]);
    __syncthreads();

#pragma unroll
    for (int h = 0; h < 2; ++h) {
      const int sw = ((qd + 4 * h) ^ (l15 & 7)) * 8;   // de-swizzle
      bf16x8 af[2], bfr[2];
#pragma unroll
      for (int r = 0; r < 2; ++r)
        af[r] = __builtin_bit_cast(bf16x8,
                  *(const u16x8*)&As[(wm + r * 16 + l15) * BK + sw]);
#pragma unroll
      for (int c = 0; c < 2; ++c)
        bfr[c] = __builtin_bit_cast(bf16x8,
                  *(const u16x8*)&Bs[(wn + c * 16 + l15) * BK + sw]);
#pragma unroll
      for (int r = 0; r < 2; ++r)
#pragma unroll
        for (int c = 0; c < 2; ++c)
          acc[r][c] = __builtin_amdgcn_mfma_f32_16x16x32_bf16(af[r], bfr[c],
                                                              acc[r][c], 0, 0, 0);
    }
    __syncthreads();
  }

  // epilogue: scatter rows via table; C/D layout col=lane&15, row=quad*4+reg
#pragma unroll
  for (int r = 0; r < 2; ++r) {
#pragma unroll
    for (int i = 0; i < 4; ++i) {
      const int slot = mtile * BM + wm + r * 16 + qd * 4 + i;
      if (slot < nb) {
        const int rowg = table[bucket * CAP + slot];
#pragma unroll
        for (int c = 0; c < 2; ++c) {
          const int col = ntile * BN + wn + c * 16 + l15;
          C[(size_t)rowg * FDIM + col] = acc[r][c][i];
        }
      }
    }
  }
}

// ---------------------------------------------------------------------------
extern "C" void kernel_launch(void* const* d_in, const int* in_sizes, int n_in,
                              void* d_out, int out_size, void* d_ws, size_t ws_size,
                              hipStream_t stream) {
  (void)in_sizes; (void)n_in; (void)out_size; (void)ws_size;
  const float* f0 = (const float*)d_in[0];
  const float* f1 = (const float*)d_in[1];
  const float* f2 = (const float*)d_in[2];
  const float* f3 = (const float*)d_in[3];
  const float* gw = (const float*)d_in[4];
  const float* gb = (const float*)d_in[5];
  const float* w0 = (const float*)d_in[6];
  const float* b0 = (const float*)d_in[7];
  const float* w1 = (const float*)d_in[8];
  const float* b1 = (const float*)d_in[9];
  const float* w2 = (const float*)d_in[10];
  const float* b2 = (const float*)d_in[11];
  const float* w3 = (const float*)d_in[12];
  const float* b3 = (const float*)d_in[13];
  float* out = (float*)d_out;

  char* ws = (char*)d_ws;
  u16* wp    = (u16*)ws;                                   // 2048*2624*2 B
  u16* fs    = (u16*)(ws + (size_t)FDIM * KP * 2);         // FS_TOTAL*2 B
  int* cnt   = (int*)(ws + (size_t)FDIM * KP * 2 + (size_t)FS_TOTAL * 2);
  int* table = cnt + 16;                                   // 6*CAP ints

  hipLaunchKernelGGL(zero_kernel, dim3(1), dim3(64), 0, stream, cnt);
  hipLaunchKernelGGL(prep_kernel, dim3(PACK_BLOCKS + GATE_BLOCKS), dim3(512), 0,
                     stream, f0, f1, f2, f3, gw, gb,
                     w0, w1, w2, w3, b0, b1, b2, b3, wp, fs, cnt, table);
  hipLaunchKernelGGL(gemm_kernel, dim3(6 * 16 * 16), dim3(512), 0, stream,
                     fs, wp, cnt, table, out);
}